// Round 8
// baseline (380.295 us; speedup 1.0000x reference)
//
#include <hip/hip_runtime.h>

#define H_DIM 768
#define C_DIM 512
#define L_DIM 256
#define S_DIM 2048
#define B_DIM 16

#define IA_STRIDE 520   // 512 + 8: lane stride 1040B = 260 dw = 4 mod 32 banks
#define ATTN_STRIDE 264 // 256 + 8: lane stride 528B = 132 dw = 4 mod 32 banks

typedef __attribute__((ext_vector_type(8))) short short8;
typedef __attribute__((ext_vector_type(4))) float f32x4;
typedef __attribute__((ext_vector_type(2))) __fp16 half2v;   // cvt_pkrtz return type

#define MFMA_F16(a, b, c) __builtin_amdgcn_mfma_f32_16x16x32_f16((a), (b), (c), 0, 0, 0)

__device__ __forceinline__ unsigned short f2h(float f) {
    _Float16 h = (_Float16)f;
    return __builtin_bit_cast(unsigned short, h);
}
__device__ __forceinline__ float h2f(unsigned short u) {
    _Float16 h = __builtin_bit_cast(_Float16, u);
    return (float)h;
}
__device__ __forceinline__ float sigmoid_f(float x) { return 1.0f / (1.0f + __expf(-x)); }

__device__ __forceinline__ short8 cvt8(const float* p) {
    const float4* q = (const float4*)(const void*)p;
    float4 u = q[0], v = q[1];
    half2v h0 = __builtin_amdgcn_cvt_pkrtz(u.x, u.y);
    half2v h1 = __builtin_amdgcn_cvt_pkrtz(u.z, u.w);
    half2v h2 = __builtin_amdgcn_cvt_pkrtz(v.x, v.y);
    half2v h3 = __builtin_amdgcn_cvt_pkrtz(v.z, v.w);
    int4 pk = { __builtin_bit_cast(int, h0), __builtin_bit_cast(int, h1),
                __builtin_bit_cast(int, h2), __builtin_bit_cast(int, h3) };
    return __builtin_bit_cast(short8, pk);
}

// ---------------------------------------------------------------------------
// Frag layouts. Element within frag: lane = (n&15) | (((k>>3)&3)<<4), j = k&7;
// addr = (frag*64 + lane)*8 + j.  Per-wave per-kt runs are 4 KB contiguous:
//   W  (n=c 32 ct, k=h 24 kt): frag = ((ct>>2)*24 + kt)*4 + (ct&3)
//   x  (m 2048 mt, k=h 24 kt): frag = ((mt>>2)*24 + kt)*4 + (mt&3)
//   la (n=l 16 lt, k=c 16 kt): frag = ((lt>>1)*16 + kt)*2 + (lt&1)
//   lt (n=c 32 ct, k=l  8 kt): frag = ((ct>>2)*8  + kt)*4 + (ct&3)
// ---------------------------------------------------------------------------

// Kernel 0: one launch = x repack (nx blocks) + W repack (768) + fusion zero (1).
__global__ __launch_bounds__(256) void prep_all(
    const float* __restrict__ x,
    const float* __restrict__ Wi, const float* __restrict__ Wia,
    const float* __restrict__ Wl, const float* __restrict__ Wla,
    unsigned short* __restrict__ x_f,
    unsigned short* __restrict__ Wi_f, unsigned short* __restrict__ Wia_f,
    unsigned short* __restrict__ Wl_f, unsigned short* __restrict__ Wla_f,
    float* __restrict__ fusion, int nx)
{
    int bid = blockIdx.x;
    if (bid < nx) {     // ---- x repack: 12288 blocks ----
        const int tid = bid * 256 + threadIdx.x;     // over 2048*24*64
        const int mt  = tid / 1536;
        const int rem = tid - mt * 1536;
        const int kt  = rem >> 6;
        const int lane = rem & 63;
        const int row = mt * 16 + (lane & 15);
        const int col = kt * 32 + (lane >> 4) * 8;
        short8 v = cvt8(x + (size_t)row * H_DIM + col);
        const int frag = ((mt >> 2) * 24 + kt) * 4 + (mt & 3);
        *(short8*)(void*)(x_f + ((size_t)frag * 64 + lane) * 8) = v;
        return;
    }
    bid -= nx;
    if (bid < 768) {    // ---- W repack: 4 matrices ----
        const int tid = bid * 256 + threadIdx.x;     // over 4*49152
        const int m   = tid / 49152;
        const int idx = tid - m * 49152;
        const int ct   = idx / 1536;          // 0..31
        const int rem  = idx - ct * 1536;
        const int kt   = rem >> 6;            // 0..23
        const int lane = rem & 63;
        const int row  = ct * 16 + (lane & 15);
        const int kcol = kt * 32 + (lane >> 4) * 8;
        const float* src = (m == 0 ? Wi : (m == 1 ? Wia : (m == 2 ? Wl : Wla)));
        unsigned short* dst = (m == 0 ? Wi_f : (m == 1 ? Wia_f : (m == 2 ? Wl_f : Wla_f)));
        short8 v = cvt8(src + (size_t)row * H_DIM + kcol);
        const int frag = ((ct >> 2) * 24 + kt) * 4 + (ct & 3);
        *(short8*)(void*)(dst + ((size_t)frag * 64 + lane) * 8) = v;
        return;
    }
    // ---- fusion zero ----
    for (int i = threadIdx.x; i < B_DIM * C_DIM; i += 256) fusion[i] = 0.f;
}

// ---------------------------------------------------------------------------
// Kernel 1: label-side joint MFMA GEMM. Grid 128 = 8 ct2 x 16 mh(16 labels).
// Wave: ct = ct2*4+wave (16 cols), 1 m-tile. Contiguous frag-W B loads.
// ---------------------------------------------------------------------------
__global__ __launch_bounds__(256) void label_mfma(
    const float* __restrict__ lab,
    const unsigned short* __restrict__ Wl_f,  const float* __restrict__ bl,
    const unsigned short* __restrict__ Wla_f, const float* __restrict__ bla,
    const float* __restrict__ ctx,
    unsigned short* __restrict__ la_f,
    unsigned short* __restrict__ lt_f)
{
    const int tid  = threadIdx.x;
    const int wave = tid >> 6;
    const int lane = tid & 63;
    const int quad = lane >> 4;
    const int c16  = lane & 15;
    const int ct2  = blockIdx.x & 7;
    const int mh   = blockIdx.x >> 3;    // 0..15
    const int n0   = (ct2 * 4 + wave) * 16;
    const int l0   = mh * 16;

    const f32x4 z4 = {0.f, 0.f, 0.f, 0.f};
    f32x4 a1 = z4, a2 = z4;

    const float* lb = lab + (size_t)(l0 + c16) * H_DIM + quad * 8;
    const short8* wl8  = (const short8*)(const void*)Wl_f  + ((size_t)ct2 * 96 + wave) * 64 + lane;
    const short8* wla8 = (const short8*)(const void*)Wla_f + ((size_t)ct2 * 96 + wave) * 64 + lane;
    for (int kt = 0; kt < 24; ++kt) {
        short8 b1 = wl8[kt * 4 * 64];
        short8 b2 = wla8[kt * 4 * 64];
        short8 a  = cvt8(lb + kt * 32);
        a1 = MFMA_F16(a, b1, a1);
        a2 = MFMA_F16(a, b2, a2);
    }
    const int c = n0 + c16;
    const float blv = bl[c], blav = bla[c], cv = ctx[c];
#pragma unroll
    for (int r = 0; r < 4; ++r) {
        const int l = l0 + quad * 4 + r;
        const float ltv = sigmoid_f(a1[r] + blv);
        const float lav = sigmoid_f(a2[r] + blav) * cv;
        {   // lt_f: n=c, k=l
            const int ctc = c >> 4, ktl = l >> 5;
            const int frag = ((ctc >> 2) * 8 + ktl) * 4 + (ctc & 3);
            const int ln = (c & 15) | (((l >> 3) & 3) << 4);
            lt_f[((size_t)frag * 64 + ln) * 8 + (l & 7)] = f2h(ltv);
        }
        {   // la_f: n=l, k=c
            const int lt = l >> 4, ktc = c >> 5;
            const int frag = ((lt >> 1) * 16 + ktc) * 2 + (lt & 1);
            const int ln = (l & 15) | (((c >> 3) & 3) << 4);
            la_f[((size_t)frag * 64 + ln) * 8 + (c & 7)] = f2h(lav);
        }
    }
}

// ---------------------------------------------------------------------------
// Kernel 2: fused main. One block = 64 rows, 512 threads (8 waves).
// Wave owns 64 C-cols (phases 1/4/5) and 32 L-cols (phase 2); 4 m-tiles.
// Halves the per-row weight stream vs 32-row blocks (L2 traffic 2.15->1.1 GB).
// acc peak = 64 VGPRs; (512,4) -> VGPR<=128 -> 2 blocks/CU, 16 waves/CU.
// ---------------------------------------------------------------------------
template<bool XF>
__global__ __launch_bounds__(512, 4) void fused_main(
    const unsigned short* __restrict__ x_f,     // A-frag f16 (XF only)
    const float* __restrict__ x,                // f32 (fallback only)
    const float* __restrict__ bi,
    const float* __restrict__ bia,
    const unsigned short* __restrict__ Wi_f,
    const unsigned short* __restrict__ Wia_f,
    const unsigned short* __restrict__ lt_f,
    const unsigned short* __restrict__ la_f,
    float* __restrict__ fusion)                 // f32 [B][C]
{
    __shared__ unsigned short lds_buf[64 * IA_STRIDE]; // ia / attn(head) / wgt
    __shared__ float rowscratch[8 * 64];
    __shared__ float inv_lds[64];

    const int tid  = threadIdx.x;
    const int wave = tid >> 6;
    const int lane = tid & 63;
    const int quad = lane >> 4;
    const int c16  = lane & 15;

    const int row0 = blockIdx.x * 64;
    const int b    = row0 >> 11;   // / 2048

    const f32x4 z4 = {0.f, 0.f, 0.f, 0.f};
    const int n0  = wave * 64;     // C-column split (phases 1/4/5)
    const int n0l = wave * 32;     // L-column split (phase 2)

    const float*  xb  = x + (size_t)(row0 + c16) * H_DIM + quad * 8;
    const short8* xf8 = (const short8*)(const void*)x_f + ((size_t)blockIdx.x * 96) * 64 + lane;

    // ========== Phase 1: ia = x@Wia^T (K=768), sigmoid -> LDS =============
    {
        f32x4 acc[4][4];
#pragma unroll
        for (int m = 0; m < 4; ++m)
#pragma unroll
            for (int p = 0; p < 4; ++p) acc[m][p] = z4;
        const short8* wa8 = (const short8*)(const void*)Wia_f + ((size_t)wave * 96) * 64 + lane;
        for (int kt = 0; kt < 24; ++kt) {
            short8 a[4], bw[4];
#pragma unroll
            for (int m = 0; m < 4; ++m) {
                if constexpr (XF) a[m] = xf8[(kt * 4 + m) * 64];
                else a[m] = cvt8(xb + m * 16 * H_DIM + kt * 32);
            }
#pragma unroll
            for (int p = 0; p < 4; ++p) bw[p] = wa8[(kt * 4 + p) * 64];
#pragma unroll
            for (int m = 0; m < 4; ++m)
#pragma unroll
                for (int p = 0; p < 4; ++p) acc[m][p] = MFMA_F16(a[m], bw[p], acc[m][p]);
        }
#pragma unroll
        for (int p = 0; p < 4; ++p) {
            const int col = n0 + p * 16 + c16;
            const float bv = bia[col];
#pragma unroll
            for (int m = 0; m < 4; ++m)
#pragma unroll
                for (int r = 0; r < 4; ++r) {
                    const int row = m * 16 + quad * 4 + r;
                    lds_buf[row * IA_STRIDE + col] = f2h(sigmoid_f(acc[m][p][r] + bv));
                }
        }
    }
    __syncthreads();

    // ========== Phase 2: logits = ia @ la^T (K=512) =======================
    f32x4 accl[4][2];
#pragma unroll
    for (int m = 0; m < 4; ++m) { accl[m][0] = z4; accl[m][1] = z4; }
    {
        const unsigned short* ab = lds_buf + c16 * IA_STRIDE + quad * 8;
        const short8* la8 = (const short8*)(const void*)la_f + ((size_t)wave * 32) * 64 + lane;
        for (int kt = 0; kt < 16; ++kt) {
            const int kk = kt * 32;
            short8 a[4], bq[2];
#pragma unroll
            for (int m = 0; m < 4; ++m)
                a[m] = *(const short8*)(const void*)(ab + m * 16 * IA_STRIDE + kk);
            bq[0] = la8[(kt * 2 + 0) * 64];
            bq[1] = la8[(kt * 2 + 1) * 64];
#pragma unroll
            for (int m = 0; m < 4; ++m) {
                accl[m][0] = MFMA_F16(a[m], bq[0], accl[m][0]);
                accl[m][1] = MFMA_F16(a[m], bq[1], accl[m][1]);
            }
        }
    }
    __syncthreads();   // all ia reads complete; lds_buf reusable

    // ========== Phase 3: softmax over L (unnormalized; keep 1/sum) ========
    float rmax[4][4];
#pragma unroll
    for (int m = 0; m < 4; ++m)
#pragma unroll
        for (int r = 0; r < 4; ++r) {
            float mm = fmaxf(accl[m][0][r], accl[m][1][r]);
#pragma unroll
            for (int off = 1; off < 16; off <<= 1) mm = fmaxf(mm, __shfl_xor(mm, off, 64));
            rmax[m][r] = mm;
        }
    if (c16 == 0) {
#pragma unroll
        for (int m = 0; m < 4; ++m)
#pragma unroll
            for (int r = 0; r < 4; ++r)
                rowscratch[wave * 64 + m * 16 + quad * 4 + r] = rmax[m][r];
    }
    __syncthreads();
    float rsum[4][4];
#pragma unroll
    for (int m = 0; m < 4; ++m)
#pragma unroll
        for (int r = 0; r < 4; ++r) {
            const int row = m * 16 + quad * 4 + r;
            float gm = rowscratch[row];
#pragma unroll
            for (int w = 1; w < 8; ++w) gm = fmaxf(gm, rowscratch[w * 64 + row]);
            float e0 = __expf(accl[m][0][r] - gm);
            float e1 = __expf(accl[m][1][r] - gm);
            accl[m][0][r] = e0; accl[m][1][r] = e1;
            float s = e0 + e1;
#pragma unroll
            for (int off = 1; off < 16; off <<= 1) s += __shfl_xor(s, off, 64);
            rsum[m][r] = s;
        }
    __syncthreads();   // maxima consumed
    if (c16 == 0) {
#pragma unroll
        for (int m = 0; m < 4; ++m)
#pragma unroll
            for (int r = 0; r < 4; ++r)
                rowscratch[wave * 64 + m * 16 + quad * 4 + r] = rsum[m][r];
    }
    __syncthreads();
#pragma unroll
    for (int m = 0; m < 4; ++m)
#pragma unroll
        for (int r = 0; r < 4; ++r) {
            const int row = m * 16 + quad * 4 + r;
            float st = rowscratch[row];
#pragma unroll
            for (int w = 1; w < 8; ++w) st += rowscratch[w * 64 + row];
            if (wave == 0 && c16 == 0) inv_lds[row] = 1.0f / st;
            lds_buf[row * ATTN_STRIDE + n0l + 0 * 16 + c16] = f2h(accl[m][0][r]);
            lds_buf[row * ATTN_STRIDE + n0l + 1 * 16 + c16] = f2h(accl[m][1][r]);
        }
    __syncthreads();

    // ========== Phase 4: weighted = attn @ lt (K=256) =====================
    f32x4 accw[4][4];
#pragma unroll
    for (int m = 0; m < 4; ++m)
#pragma unroll
        for (int p = 0; p < 4; ++p) accw[m][p] = z4;
    {
        const unsigned short* ab = lds_buf + c16 * ATTN_STRIDE + quad * 8;
        const short8* lt8 = (const short8*)(const void*)lt_f + ((size_t)wave * 32) * 64 + lane;
        for (int kt = 0; kt < 8; ++kt) {
            const int kk = kt * 32;
            short8 a[4], bp[4];
#pragma unroll
            for (int m = 0; m < 4; ++m)
                a[m] = *(const short8*)(const void*)(ab + m * 16 * ATTN_STRIDE + kk);
#pragma unroll
            for (int p = 0; p < 4; ++p) bp[p] = lt8[(kt * 4 + p) * 64];
#pragma unroll
            for (int m = 0; m < 4; ++m)
#pragma unroll
                for (int p = 0; p < 4; ++p) accw[m][p] = MFMA_F16(a[m], bp[p], accw[m][p]);
        }
    }
    __syncthreads();   // all attn reads complete; lds_buf reusable for wgt

    // spill wgt = weighted * invsum to LDS (f16); col-disjoint per wave
    {
        float invr[4][4];
#pragma unroll
        for (int m = 0; m < 4; ++m)
#pragma unroll
            for (int r = 0; r < 4; ++r) invr[m][r] = inv_lds[m * 16 + quad * 4 + r];
#pragma unroll
        for (int p = 0; p < 4; ++p) {
            const int col = n0 + p * 16 + c16;
#pragma unroll
            for (int m = 0; m < 4; ++m)
#pragma unroll
                for (int r = 0; r < 4; ++r) {
                    const int row = m * 16 + quad * 4 + r;
                    lds_buf[row * IA_STRIDE + col] = f2h(accw[m][p][r] * invr[m][r]);
                }
        }
    }
    // no barrier: phase 5 reads only this wave's own cols

    // ========== Phase 5: it = x@Wi^T (recompute), fusion + atomics ========
    {
        f32x4 acc[4][4];
#pragma unroll
        for (int m = 0; m < 4; ++m)
#pragma unroll
            for (int p = 0; p < 4; ++p) acc[m][p] = z4;
        const short8* wi8 = (const short8*)(const void*)Wi_f + ((size_t)wave * 96) * 64 + lane;
        for (int kt = 0; kt < 24; ++kt) {
            short8 a[4], bw[4];
#pragma unroll
            for (int m = 0; m < 4; ++m) {
                if constexpr (XF) a[m] = xf8[(kt * 4 + m) * 64];
                else a[m] = cvt8(xb + m * 16 * H_DIM + kt * 32);
            }
#pragma unroll
            for (int p = 0; p < 4; ++p) bw[p] = wi8[(kt * 4 + p) * 64];
#pragma unroll
            for (int m = 0; m < 4; ++m)
#pragma unroll
                for (int p = 0; p < 4; ++p) acc[m][p] = MFMA_F16(a[m], bw[p], acc[m][p]);
        }
#pragma unroll
        for (int p = 0; p < 4; ++p) {
            const int col = n0 + p * 16 + c16;
            const float bv = bi[col];
            float s = 0.f;
#pragma unroll
            for (int m = 0; m < 4; ++m)
#pragma unroll
                for (int r = 0; r < 4; ++r) {
                    const int row = m * 16 + quad * 4 + r;
                    s += h2f(lds_buf[row * IA_STRIDE + col]) * sigmoid_f(acc[m][p][r] + bv);
                }
            s += __shfl_xor(s, 16, 64);
            s += __shfl_xor(s, 32, 64);
            if (lane < 16) atomicAdd(&fusion[b * C_DIM + col], s);
        }
    }
}

// ---------------------------------------------------------------------------
// Kernel 3: out[b][h] = sum_c fusion[b][c] * Wp[h][c]. 8 lanes per row.
// ---------------------------------------------------------------------------
__global__ __launch_bounds__(256) void out_kernel(
    const float* __restrict__ fusion,
    const float* __restrict__ Wp,
    float* __restrict__ out)
{
    const int idx = blockIdx.x * 256 + threadIdx.x;
    const int R   = idx >> 3;
    const int sub = idx & 7;
    const int bb  = R / H_DIM;
    const int h   = R - bb * H_DIM;
    const float* wp = Wp + (size_t)h * C_DIM;
    const float* f  = fusion + bb * C_DIM;
    float s = 0.f;
#pragma unroll
    for (int j = 0; j < 16; ++j) {
        const int c = j * 32 + sub * 4;
        float4 wv = *(const float4*)(const void*)(wp + c);
        float4 fv = *(const float4*)(const void*)(f + c);
        s += fv.x * wv.x + fv.y * wv.y + fv.z * wv.z + fv.w * wv.w;
    }
    s += __shfl_xor(s, 1, 64);
    s += __shfl_xor(s, 2, 64);
    s += __shfl_xor(s, 4, 64);
    if (sub == 0) out[R] = s;
}

extern "C" void kernel_launch(void* const* d_in, const int* in_sizes, int n_in,
                              void* d_out, int out_size, void* d_ws, size_t ws_size,
                              hipStream_t stream)
{
    const float* x    = (const float*)d_in[0];
    const float* lab  = (const float*)d_in[1];
    const float* Wi   = (const float*)d_in[2];
    const float* bi   = (const float*)d_in[3];
    const float* Wl   = (const float*)d_in[4];
    const float* bl   = (const float*)d_in[5];
    const float* Wia  = (const float*)d_in[6];
    const float* bia  = (const float*)d_in[7];
    const float* Wla  = (const float*)d_in[8];
    const float* bla  = (const float*)d_in[9];
    const float* ctx  = (const float*)d_in[10];
    const float* Wp   = (const float*)d_in[11];

    char* ws = (char*)d_ws;
    unsigned short* Wi_f  = (unsigned short*)(ws);               // 768 KB
    unsigned short* Wia_f = (unsigned short*)(ws + 786432);      // 768 KB
    unsigned short* Wl_f  = (unsigned short*)(ws + 1572864);     // 768 KB
    unsigned short* Wla_f = (unsigned short*)(ws + 2359296);     // 768 KB
    unsigned short* la_f  = (unsigned short*)(ws + 3145728);     // 256 KB
    unsigned short* lt_f  = (unsigned short*)(ws + 3407872);     // 256 KB
    float* fusion         = (float*)(ws + 3670016);              // 32 KB
    unsigned short* x_f   = (unsigned short*)(ws + 3702784);     // 48 MB (optional)
    const size_t NEED_XF  = 3702784 + (size_t)32768 * 768 * 2;   // ~51.5 MB

    const bool xf = (ws_size >= NEED_XF);
    const int nx = xf ? 12288 : 0;
    prep_all<<<nx + 769, 256, 0, stream>>>(x, Wi, Wia, Wl, Wla,
                                           x_f, Wi_f, Wia_f, Wl_f, Wla_f, fusion, nx);
    label_mfma<<<128, 256, 0, stream>>>(lab, Wl_f, bl, Wla_f, bla, ctx, la_f, lt_f);
    if (xf) {
        fused_main<true><<<(B_DIM * S_DIM) / 64, 512, 0, stream>>>(
            x_f, x, bi, bia, Wi_f, Wia_f, lt_f, la_f, fusion);
    } else {
        fused_main<false><<<(B_DIM * S_DIM) / 64, 512, 0, stream>>>(
            nullptr, x, bi, bia, Wi_f, Wia_f, lt_f, la_f, fusion);
    }
    out_kernel<<<384, 256, 0, stream>>>(fusion, Wp, (float*)d_out);
}

// Round 9
// 338.944 us; speedup vs baseline: 1.1220x; 1.1220x over previous
//
#include <hip/hip_runtime.h>

#define H_DIM 768
#define C_DIM 512
#define L_DIM 256
#define S_DIM 2048
#define B_DIM 16

#define IA_STRIDE 520   // 512 + 8: lane stride 1040B = 260 dw = 4 mod 32 banks
#define ATTN_STRIDE 264 // 256 + 8: lane stride 528B = 132 dw = 4 mod 32 banks

typedef __attribute__((ext_vector_type(8))) short short8;
typedef __attribute__((ext_vector_type(4))) float f32x4;
typedef __attribute__((ext_vector_type(2))) __fp16 half2v;   // cvt_pkrtz return type

#define MFMA_F16(a, b, c) __builtin_amdgcn_mfma_f32_16x16x32_f16((a), (b), (c), 0, 0, 0)

__device__ __forceinline__ unsigned short f2h(float f) {
    _Float16 h = (_Float16)f;
    return __builtin_bit_cast(unsigned short, h);
}
__device__ __forceinline__ float h2f(unsigned short u) {
    _Float16 h = __builtin_bit_cast(_Float16, u);
    return (float)h;
}
__device__ __forceinline__ float sigmoid_f(float x) { return 1.0f / (1.0f + __expf(-x)); }

__device__ __forceinline__ short8 cvt8(const float* p) {
    const float4* q = (const float4*)(const void*)p;
    float4 u = q[0], v = q[1];
    half2v h0 = __builtin_amdgcn_cvt_pkrtz(u.x, u.y);
    half2v h1 = __builtin_amdgcn_cvt_pkrtz(u.z, u.w);
    half2v h2 = __builtin_amdgcn_cvt_pkrtz(v.x, v.y);
    half2v h3 = __builtin_amdgcn_cvt_pkrtz(v.z, v.w);
    int4 pk = { __builtin_bit_cast(int, h0), __builtin_bit_cast(int, h1),
                __builtin_bit_cast(int, h2), __builtin_bit_cast(int, h3) };
    return __builtin_bit_cast(short8, pk);
}

// ---------------------------------------------------------------------------
// Frag layouts (one wave frag load = 64 lanes x 16 B = 1 KB contiguous):
//   B operand M[n][k]: lane = (n&15) | (((k>>3)&3)<<4), j = k&7
//     W  (n 32 ct, k 24 kt): frag = ((ct>>3)*24 + kt)*8 + (ct&7)
//     la (n 16 lt, k 16 kt): frag = ((lt>>2)*16 + kt)*4 + (lt&3)
//     lt (n 32 ct, k  8 kt): frag = ((ct>>3)*8  + kt)*8 + (ct&7)
//   A operand x[m][k]: lane = (m&15) | (((k>>3)&3)<<4), j = k&7
//     x  (m 2048 mt, k 24 kt): frag = mt*24 + kt
// ---------------------------------------------------------------------------

// Kernel 0: ONE launch = label GEMM (128 blocks, first: latency-bound, hides
// under the streaming blocks) + x repack (nx) + Wi/Wia repack (384) + zero (1).
__global__ __launch_bounds__(256) void prep_all(
    const float* __restrict__ x,
    const float* __restrict__ Wi, const float* __restrict__ Wia,
    const float* __restrict__ lab,
    const float* __restrict__ Wl,  const float* __restrict__ bl,
    const float* __restrict__ Wla, const float* __restrict__ bla,
    const float* __restrict__ ctx,
    unsigned short* __restrict__ x_f,
    unsigned short* __restrict__ Wi_f, unsigned short* __restrict__ Wia_f,
    unsigned short* __restrict__ la_f, unsigned short* __restrict__ lt_f,
    float* __restrict__ fusion, int nx)
{
    int bid = blockIdx.x;
    if (bid < 128) {    // ---- label-side joint MFMA GEMM (f32 W, cvt8) ----
        const int tid  = threadIdx.x;
        const int wave = tid >> 6;
        const int lane = tid & 63;
        const int quad = lane >> 4;
        const int c16  = lane & 15;
        const int ct2  = bid & 7;
        const int mh   = bid >> 3;           // 0..15
        const int n0   = (ct2 * 4 + wave) * 16;
        const int l0   = mh * 16;

        const f32x4 z4 = {0.f, 0.f, 0.f, 0.f};
        f32x4 a1 = z4, a2 = z4;
        const float* lb  = lab + (size_t)(l0 + c16) * H_DIM + quad * 8;
        const float* wl  = Wl  + (size_t)(n0 + c16) * H_DIM + quad * 8;
        const float* wla = Wla + (size_t)(n0 + c16) * H_DIM + quad * 8;
        for (int kt = 0; kt < 24; ++kt) {
            short8 b1 = cvt8(wl + kt * 32);
            short8 b2 = cvt8(wla + kt * 32);
            short8 a  = cvt8(lb + kt * 32);
            a1 = MFMA_F16(a, b1, a1);
            a2 = MFMA_F16(a, b2, a2);
        }
        const int c = n0 + c16;
        const float blv = bl[c], blav = bla[c], cv = ctx[c];
#pragma unroll
        for (int r = 0; r < 4; ++r) {
            const int l = l0 + quad * 4 + r;
            const float ltv = sigmoid_f(a1[r] + blv);
            const float lav = sigmoid_f(a2[r] + blav) * cv;
            {   // lt_f: n=c, k=l
                const int ctc = c >> 4, ktl = l >> 5;
                const int frag = ((ctc >> 3) * 8 + ktl) * 8 + (ctc & 7);
                const int ln = (c & 15) | (((l >> 3) & 3) << 4);
                lt_f[((size_t)frag * 64 + ln) * 8 + (l & 7)] = f2h(ltv);
            }
            {   // la_f: n=l, k=c
                const int lt = l >> 4, ktc = c >> 5;
                const int frag = ((lt >> 2) * 16 + ktc) * 4 + (lt & 3);
                const int ln = (l & 15) | (((c >> 3) & 3) << 4);
                la_f[((size_t)frag * 64 + ln) * 8 + (c & 7)] = f2h(lav);
            }
        }
        return;
    }
    bid -= 128;
    if (bid < nx) {     // ---- x repack: 12288 blocks ----
        const int tid = bid * 256 + threadIdx.x;     // over 2048*24*64
        const int mt  = tid / 1536;
        const int rem = tid - mt * 1536;
        const int kt  = rem >> 6;
        const int lane = rem & 63;
        const int row = mt * 16 + (lane & 15);
        const int col = kt * 32 + (lane >> 4) * 8;
        short8 v = cvt8(x + (size_t)row * H_DIM + col);
        *(short8*)(void*)(x_f + ((size_t)(mt * 24 + kt) * 64 + lane) * 8) = v;
        return;
    }
    bid -= nx;
    if (bid < 384) {    // ---- Wi/Wia repack ----
        const int tid = bid * 256 + threadIdx.x;     // over 2*49152
        const int m   = tid / 49152;
        const int idx = tid - m * 49152;
        const int ct   = idx / 1536;          // 0..31
        const int rem  = idx - ct * 1536;
        const int kt   = rem >> 6;            // 0..23
        const int lane = rem & 63;
        const int row  = ct * 16 + (lane & 15);
        const int kcol = kt * 32 + (lane >> 4) * 8;
        const float* src = (m == 0 ? Wi : Wia);
        unsigned short* dst = (m == 0 ? Wi_f : Wia_f);
        short8 v = cvt8(src + (size_t)row * H_DIM + kcol);
        const int frag = ((ct >> 3) * 24 + kt) * 8 + (ct & 7);
        *(short8*)(void*)(dst + ((size_t)frag * 64 + lane) * 8) = v;
        return;
    }
    // ---- fusion zero ----
    for (int i = threadIdx.x; i < B_DIM * C_DIM; i += 256) fusion[i] = 0.f;
}

// ---------------------------------------------------------------------------
// Kernel 1: fused main — VERBATIM R7 structure (146 us, no spills).
// One block = 32 rows, 256 threads (4 waves), (256,4) -> 4 blocks/CU.
// ---------------------------------------------------------------------------
template<bool XF>
__global__ __launch_bounds__(256, 4) void fused_main(
    const unsigned short* __restrict__ x_f,     // A-frag f16 (XF only)
    const float* __restrict__ x,                // f32 (fallback only)
    const float* __restrict__ bi,
    const float* __restrict__ bia,
    const unsigned short* __restrict__ Wi_f,
    const unsigned short* __restrict__ Wia_f,
    const unsigned short* __restrict__ lt_f,
    const unsigned short* __restrict__ la_f,
    float* __restrict__ fusion)                 // f32 [B][C]
{
    __shared__ unsigned short lds_buf[32 * IA_STRIDE]; // ia / attn(head) / wgt
    __shared__ float rowscratch[4 * 32];
    __shared__ float inv_lds[32];

    const int tid  = threadIdx.x;
    const int wave = tid >> 6;
    const int lane = tid & 63;
    const int quad = lane >> 4;
    const int c16  = lane & 15;

    const int row0 = blockIdx.x * 32;
    const int b    = row0 >> 11;   // / 2048

    const f32x4 z4 = {0.f, 0.f, 0.f, 0.f};
    const int n0 = wave * 128;     // C-column split

    const float*  xb  = x + (size_t)(row0 + c16) * H_DIM + quad * 8;
    const short8* xf8 = (const short8*)(const void*)x_f + ((size_t)blockIdx.x * 2 * 24) * 64 + lane;

    // ========== Phase 1: ia = x@Wia^T (K=768), sigmoid -> LDS =============
    {
        f32x4 acc[2][8];
#pragma unroll
        for (int mt = 0; mt < 2; ++mt)
#pragma unroll
            for (int nt = 0; nt < 8; ++nt) acc[mt][nt] = z4;
        const short8* wa8 = (const short8*)(const void*)Wia_f + (size_t)wave * 192 * 64 + lane;
        for (int kt = 0; kt < 24; ++kt) {
            short8 a0, a1;
            if constexpr (XF) { a0 = xf8[kt * 64]; a1 = xf8[(24 + kt) * 64]; }
            else { a0 = cvt8(xb + kt * 32); a1 = cvt8(xb + 16 * H_DIM + kt * 32); }
#pragma unroll
            for (int nt = 0; nt < 8; ++nt) {
                short8 ba = wa8[(kt * 8 + nt) * 64];
                acc[0][nt] = MFMA_F16(a0, ba, acc[0][nt]);
                acc[1][nt] = MFMA_F16(a1, ba, acc[1][nt]);
            }
        }
#pragma unroll
        for (int nt = 0; nt < 8; ++nt) {
            const int col = n0 + nt * 16 + c16;
            const float bv = bia[col];
#pragma unroll
            for (int mt = 0; mt < 2; ++mt)
#pragma unroll
                for (int r = 0; r < 4; ++r) {
                    const int row = mt * 16 + quad * 4 + r;
                    lds_buf[row * IA_STRIDE + col] = f2h(sigmoid_f(acc[mt][nt][r] + bv));
                }
        }
    }
    __syncthreads();

    // ========== Phase 2: logits = ia @ la^T (K=512) =======================
    const int n0l = wave * 64;   // L-column split
    f32x4 accl[2][4];
#pragma unroll
    for (int mt = 0; mt < 2; ++mt)
#pragma unroll
        for (int nt = 0; nt < 4; ++nt) accl[mt][nt] = z4;
    {
        const unsigned short* ab = lds_buf + c16 * IA_STRIDE + quad * 8;
        const short8* la8 = (const short8*)(const void*)la_f + (size_t)wave * 64 * 64 + lane;
        for (int kt = 0; kt < 16; ++kt) {
            const int kk = kt * 32;
            short8 a0 = *(const short8*)(const void*)(ab + kk);
            short8 a1 = *(const short8*)(const void*)(ab + 16 * IA_STRIDE + kk);
#pragma unroll
            for (int nt = 0; nt < 4; ++nt) {
                short8 bfr = la8[(kt * 4 + nt) * 64];
                accl[0][nt] = MFMA_F16(a0, bfr, accl[0][nt]);
                accl[1][nt] = MFMA_F16(a1, bfr, accl[1][nt]);
            }
        }
    }
    __syncthreads();   // all ia reads complete; lds_buf reusable

    // ========== Phase 3: softmax over L (unnormalized; keep 1/sum) ========
    float rmax[2][4];
#pragma unroll
    for (int mt = 0; mt < 2; ++mt)
#pragma unroll
        for (int r = 0; r < 4; ++r) {
            float m = accl[mt][0][r];
#pragma unroll
            for (int nt = 1; nt < 4; ++nt) m = fmaxf(m, accl[mt][nt][r]);
#pragma unroll
            for (int off = 1; off < 16; off <<= 1) m = fmaxf(m, __shfl_xor(m, off, 64));
            rmax[mt][r] = m;
        }
    if (c16 == 0) {
#pragma unroll
        for (int mt = 0; mt < 2; ++mt)
#pragma unroll
            for (int r = 0; r < 4; ++r)
                rowscratch[wave * 32 + mt * 16 + quad * 4 + r] = rmax[mt][r];
    }
    __syncthreads();
    float rsum[2][4];
#pragma unroll
    for (int mt = 0; mt < 2; ++mt)
#pragma unroll
        for (int r = 0; r < 4; ++r) {
            const int row = mt * 16 + quad * 4 + r;
            float gm = rowscratch[row];
#pragma unroll
            for (int w = 1; w < 4; ++w) gm = fmaxf(gm, rowscratch[w * 32 + row]);
            float s = 0.f;
#pragma unroll
            for (int nt = 0; nt < 4; ++nt) {
                float e = __expf(accl[mt][nt][r] - gm);
                accl[mt][nt][r] = e;
                s += e;
            }
#pragma unroll
            for (int off = 1; off < 16; off <<= 1) s += __shfl_xor(s, off, 64);
            rsum[mt][r] = s;
        }
    __syncthreads();   // maxima consumed
    if (c16 == 0) {
#pragma unroll
        for (int mt = 0; mt < 2; ++mt)
#pragma unroll
            for (int r = 0; r < 4; ++r)
                rowscratch[wave * 32 + mt * 16 + quad * 4 + r] = rsum[mt][r];
    }
    __syncthreads();
#pragma unroll
    for (int mt = 0; mt < 2; ++mt)
#pragma unroll
        for (int r = 0; r < 4; ++r) {
            const int row = mt * 16 + quad * 4 + r;
            const float st = rowscratch[row] + rowscratch[32 + row]
                           + rowscratch[64 + row] + rowscratch[96 + row];
            if (wave == 0 && c16 == 0) inv_lds[row] = 1.0f / st;
#pragma unroll
            for (int nt = 0; nt < 4; ++nt)
                lds_buf[row * ATTN_STRIDE + n0l + nt * 16 + c16] = f2h(accl[mt][nt][r]);
        }
    __syncthreads();

    // ========== Phase 4: weighted = attn @ lt (K=256) =====================
    f32x4 accw[2][8];
#pragma unroll
    for (int mt = 0; mt < 2; ++mt)
#pragma unroll
        for (int nt = 0; nt < 8; ++nt) accw[mt][nt] = z4;
    {
        const unsigned short* ab = lds_buf + c16 * ATTN_STRIDE + quad * 8;
        const short8* lt8 = (const short8*)(const void*)lt_f + (size_t)wave * 64 * 64 + lane;
        for (int kt = 0; kt < 8; ++kt) {
            const int kk = kt * 32;
            short8 a0 = *(const short8*)(const void*)(ab + kk);
            short8 a1 = *(const short8*)(const void*)(ab + 16 * ATTN_STRIDE + kk);
#pragma unroll
            for (int nt = 0; nt < 8; ++nt) {
                short8 bfr = lt8[(kt * 8 + nt) * 64];
                accw[0][nt] = MFMA_F16(a0, bfr, accw[0][nt]);
                accw[1][nt] = MFMA_F16(a1, bfr, accw[1][nt]);
            }
        }
    }
    __syncthreads();   // all attn reads complete; lds_buf reusable for wgt

    // spill wgt = weighted * invsum to LDS (f16); wave-private region
    {
        float invr[2][4];
#pragma unroll
        for (int mt = 0; mt < 2; ++mt)
#pragma unroll
            for (int r = 0; r < 4; ++r) invr[mt][r] = inv_lds[mt * 16 + quad * 4 + r];
#pragma unroll
        for (int nt = 0; nt < 8; ++nt) {
            const int col = n0 + nt * 16 + c16;
#pragma unroll
            for (int mt = 0; mt < 2; ++mt)
#pragma unroll
                for (int r = 0; r < 4; ++r) {
                    const int row = mt * 16 + quad * 4 + r;
                    lds_buf[row * IA_STRIDE + col] = f2h(accw[mt][nt][r] * invr[mt][r]);
                }
        }
    }
    // no barrier: phase 5 reads only this wave's own cols/rows

    // ========== Phase 5: it = x@Wi^T (recompute), fusion + atomics ========
    {
        f32x4 acc[2][8];
#pragma unroll
        for (int mt = 0; mt < 2; ++mt)
#pragma unroll
            for (int nt = 0; nt < 8; ++nt) acc[mt][nt] = z4;
        const short8* wi8 = (const short8*)(const void*)Wi_f + (size_t)wave * 192 * 64 + lane;
        for (int kt = 0; kt < 24; ++kt) {
            short8 a0, a1;
            if constexpr (XF) { a0 = xf8[kt * 64]; a1 = xf8[(24 + kt) * 64]; }
            else { a0 = cvt8(xb + kt * 32); a1 = cvt8(xb + 16 * H_DIM + kt * 32); }
#pragma unroll
            for (int nt = 0; nt < 8; ++nt) {
                short8 bw = wi8[(kt * 8 + nt) * 64];
                acc[0][nt] = MFMA_F16(a0, bw, acc[0][nt]);
                acc[1][nt] = MFMA_F16(a1, bw, acc[1][nt]);
            }
        }
#pragma unroll
        for (int nt = 0; nt < 8; ++nt) {
            const int col = n0 + nt * 16 + c16;
            const float bv = bi[col];
            float s = 0.f;
#pragma unroll
            for (int mt = 0; mt < 2; ++mt)
#pragma unroll
                for (int r = 0; r < 4; ++r) {
                    const int row = mt * 16 + quad * 4 + r;
                    s += h2f(lds_buf[row * IA_STRIDE + col]) * sigmoid_f(acc[mt][nt][r] + bv);
                }
            s += __shfl_xor(s, 16, 64);
            s += __shfl_xor(s, 32, 64);
            if (lane < 16) atomicAdd(&fusion[b * C_DIM + col], s);
        }
    }
}

// ---------------------------------------------------------------------------
// Kernel 2: out[b][h] = sum_c fusion[b][c] * Wp[h][c]. 8 lanes per row.
// ---------------------------------------------------------------------------
__global__ __launch_bounds__(256) void out_kernel(
    const float* __restrict__ fusion,
    const float* __restrict__ Wp,
    float* __restrict__ out)
{
    const int idx = blockIdx.x * 256 + threadIdx.x;
    const int R   = idx >> 3;
    const int sub = idx & 7;
    const int bb  = R / H_DIM;
    const int h   = R - bb * H_DIM;
    const float* wp = Wp + (size_t)h * C_DIM;
    const float* f  = fusion + bb * C_DIM;
    float s = 0.f;
#pragma unroll
    for (int j = 0; j < 16; ++j) {
        const int c = j * 32 + sub * 4;
        float4 wv = *(const float4*)(const void*)(wp + c);
        float4 fv = *(const float4*)(const void*)(f + c);
        s += fv.x * wv.x + fv.y * wv.y + fv.z * wv.z + fv.w * wv.w;
    }
    s += __shfl_xor(s, 1, 64);
    s += __shfl_xor(s, 2, 64);
    s += __shfl_xor(s, 4, 64);
    if (sub == 0) out[R] = s;
}

extern "C" void kernel_launch(void* const* d_in, const int* in_sizes, int n_in,
                              void* d_out, int out_size, void* d_ws, size_t ws_size,
                              hipStream_t stream)
{
    const float* x    = (const float*)d_in[0];
    const float* lab  = (const float*)d_in[1];
    const float* Wi   = (const float*)d_in[2];
    const float* bi   = (const float*)d_in[3];
    const float* Wl   = (const float*)d_in[4];
    const float* bl   = (const float*)d_in[5];
    const float* Wia  = (const float*)d_in[6];
    const float* bia  = (const float*)d_in[7];
    const float* Wla  = (const float*)d_in[8];
    const float* bla  = (const float*)d_in[9];
    const float* ctx  = (const float*)d_in[10];
    const float* Wp   = (const float*)d_in[11];

    char* ws = (char*)d_ws;
    unsigned short* Wi_f  = (unsigned short*)(ws);               // 768 KB
    unsigned short* Wia_f = (unsigned short*)(ws + 786432);      // 768 KB
    unsigned short* la_f  = (unsigned short*)(ws + 1572864);     // 256 KB
    unsigned short* lt_f  = (unsigned short*)(ws + 1835008);     // 256 KB
    float* fusion         = (float*)(ws + 2097152);              // 32 KB
    unsigned short* x_f   = (unsigned short*)(ws + 2129920);     // 48 MB (optional)
    const size_t NEED_XF  = 2129920 + (size_t)32768 * 768 * 2;   // ~50.5 MB

    const bool xf = (ws_size >= NEED_XF);
    const int nx = xf ? 12288 : 0;
    prep_all<<<128 + nx + 384 + 1, 256, 0, stream>>>(
        x, Wi, Wia, lab, Wl, bl, Wla, bla, ctx,
        x_f, Wi_f, Wia_f, la_f, lt_f, fusion, nx);
    if (xf) {
        fused_main<true><<<(B_DIM * S_DIM) / 32, 256, 0, stream>>>(
            x_f, x, bi, bia, Wi_f, Wia_f, lt_f, la_f, fusion);
    } else {
        fused_main<false><<<(B_DIM * S_DIM) / 32, 256, 0, stream>>>(
            nullptr, x, bi, bia, Wi_f, Wia_f, lt_f, la_f, fusion);
    }
    out_kernel<<<384, 256, 0, stream>>>(fusion, Wp, (float*)d_out);
}